// Round 5
// baseline (254.375 us; speedup 1.0000x reference)
//
#include <hip/hip_runtime.h>
#include <stdint.h>

// (B,T,E,H,D) = (2,2048,1024,16,64)
constexpr float INV_SCALE = 0.022097086912079608f;  // 1/sqrt(2048)
constexpr float LOG2E = 1.4426950408889634f;
constexpr float QSC = INV_SCALE * LOG2E;            // q pre-scale: softmax in exp2 domain

typedef __attribute__((ext_vector_type(8))) short bfrag;          // 8 bf16 (4 VGPR) MFMA frag
typedef __attribute__((ext_vector_type(4))) float facc;           // 4 f32 MFMA acc
typedef __attribute__((ext_vector_type(4))) unsigned short us4;   // 4 bf16 = 8B

#define MFMA(a, b, c) __builtin_amdgcn_mfma_f32_16x16x32_bf16((a), (b), (c), 0, 0, 0)
#define EXP2(x) __builtin_amdgcn_exp2f(x)

__device__ __forceinline__ unsigned short f2bh(float f) {        // f32 -> bf16 RNE
    union { float f; unsigned int u; } cv; cv.f = f;
    unsigned int u = cv.u;
    u += 0x7FFFu + ((u >> 16) & 1u);
    return (unsigned short)(u >> 16);
}
__device__ __forceinline__ float bh2f(unsigned short h) {
    union { unsigned int u; float f; } cv; cv.u = ((unsigned int)h) << 16;
    return cv.f;
}
__device__ __forceinline__ void gl_lds16(const unsigned short* g, unsigned short* lds) {
    // async 16B/lane global->LDS; dst is wave-uniform base, lane i lands at dst+16*i
    __builtin_amdgcn_global_load_lds(
        (const __attribute__((address_space(1))) unsigned int*)g,
        (__attribute__((address_space(3))) unsigned int*)lds, 16, 0, 0);
}

// ---------------------------------------------------------------------------
// prep_w: per head, transpose W[h][1024 e][64 i] -> WT[h*64+i][1024 e] with
// hi/lo bf16 split for Wq/Wk (Q/K path needs ~fp32 logits), hi-only for Wv.
// grid (16 etiles, 16 heads, 3), block 256.
// ---------------------------------------------------------------------------
__global__ __launch_bounds__(256) void prep_w(
    const float* __restrict__ Wq, const float* __restrict__ Wk, const float* __restrict__ Wv,
    unsigned short* __restrict__ WqTh, unsigned short* __restrict__ WqTl,
    unsigned short* __restrict__ WkTh, unsigned short* __restrict__ WkTl,
    unsigned short* __restrict__ WvT)
{
    __shared__ float tile[64][65];
    const int tid = threadIdx.x;
    const int et = blockIdx.x, h = blockIdx.y, m = blockIdx.z;
    const float* W = (m == 0) ? Wq : (m == 1) ? Wk : Wv;
    #pragma unroll
    for (int rep = 0; rep < 4; ++rep) {
        int idx = rep * 256 + tid;            // f4 idx over [64e][16 i4]
        int e = idx >> 4, i4 = (idx & 15) * 4;
        facc v = *(const facc*)&W[(size_t)h * 65536 + (size_t)(et * 64 + e) * 64 + i4];
        tile[e][i4] = v.x; tile[e][i4 + 1] = v.y; tile[e][i4 + 2] = v.z; tile[e][i4 + 3] = v.w;
    }
    __syncthreads();
    unsigned short* Oh = (m == 0) ? WqTh : (m == 1) ? WkTh : WvT;
    unsigned short* Ol = (m == 0) ? WqTl : WkTl;   // unused when m==2
    #pragma unroll
    for (int rep = 0; rep < 4; ++rep) {
        int idx = rep * 256 + tid;            // [64 i][16 e4]
        int i = idx >> 4, e4 = (idx & 15) * 4;
        us4 hv, lv;
        #pragma unroll
        for (int j = 0; j < 4; ++j) {
            float f = tile[e4 + j][i];
            unsigned short hb = f2bh(f);
            hv[j] = hb;
            lv[j] = f2bh(f - bh2f(hb));
        }
        size_t o = (size_t)(h * 64 + i) * 1024 + et * 64 + e4;
        *(us4*)&Oh[o] = hv;
        if (m < 2) *(us4*)&Ol[o] = lv;
    }
}

// Wo [1024 o][1024 i] fp32 -> bf16 (already B^T layout for out = att @ Wo^T)
__global__ __launch_bounds__(256) void wo_conv(const float* __restrict__ Wo,
                                               unsigned short* __restrict__ WoB) {
    int idx = blockIdx.x * 256 + threadIdx.x;   // f4 index, 262144 total
    facc v = *(const facc*)&Wo[(size_t)idx * 4];
    us4 o;
    #pragma unroll
    for (int j = 0; j < 4; ++j) o[j] = f2bh(v[j]);
    *(us4*)&WoB[(size_t)idx * 4] = o;
}

// ---------------------------------------------------------------------------
// qkv_gemm: C[4096,1024] = X @ W  per which in {q,k,v}.  128x128 tile, BK=64,
// 4 waves each 64x64.  All LDS tiles are [128][64] bf16 (128B rows) with the
// 8-slot XOR swizzle (slot ^= row&7): ds_read_b128 and ds_write_b64 are
// conflict-free (2-way max).  B staged via global_load_lds with the inverse
// swizzle applied to the per-lane GLOBAL source (LDS dest linear, rule #21).
// A staged from fp32 x with in-kernel hi/lo split, written swizzled.
// q/k: 3-term split MFMA (ah*bh + ah*bl + al*bh).  grid (32, 8, 3), block 256.
// ---------------------------------------------------------------------------
__global__ __launch_bounds__(256) void qkv_gemm(
    const float* __restrict__ x,
    const unsigned short* __restrict__ WqTh, const unsigned short* __restrict__ WqTl,
    const unsigned short* __restrict__ WkTh, const unsigned short* __restrict__ WkTl,
    const unsigned short* __restrict__ WvT,
    unsigned short* __restrict__ qh, unsigned short* __restrict__ ql,
    unsigned short* __restrict__ kh, unsigned short* __restrict__ kl,
    unsigned short* __restrict__ vT)
{
    __shared__ unsigned short Ah[128 * 64], Al[128 * 64], Bh[128 * 64], Bl[128 * 64];
    const int tid = threadIdx.x;
    const int w = tid >> 6, l = tid & 63;
    const int wm = w >> 1, wn = w & 1;
    const int rt = blockIdx.x, ct = blockIdx.y, which = blockIdx.z;
    const bool split = (which < 2);
    const unsigned short* Bhg = (which == 0) ? WqTh : (which == 1) ? WkTh : WvT;
    const unsigned short* Blg = (which == 0) ? WqTl : WkTl;

    facc acc[4][4];
    #pragma unroll
    for (int i = 0; i < 4; ++i)
        #pragma unroll
        for (int j = 0; j < 4; ++j) acc[i][j] = (facc)(0.0f);

    for (int e0 = 0; e0 < 1024; e0 += 64) {
        __syncthreads();
        // stage A: 128x64 fp32 -> bf16 hi/lo, swizzled ds_write_b64 (2-way max)
        #pragma unroll
        for (int rep = 0; rep < 8; ++rep) {
            int idx = rep * 256 + tid;          // f4 idx, 2048 total
            int row = idx >> 4, cp = idx & 15;  // 16 f4 per 64-elem row
            facc xv = *(const facc*)&x[(size_t)(rt * 128 + row) * 1024 + e0 + cp * 4];
            us4 hv, lv;
            #pragma unroll
            for (int j = 0; j < 4; ++j) {
                float f = xv[j];
                unsigned short hb = f2bh(f);
                hv[j] = hb;
                lv[j] = f2bh(f - bh2f(hb));
            }
            int slot = (cp >> 1) ^ (row & 7);
            int off = row * 64 + slot * 8 + (cp & 1) * 4;
            *(us4*)&Ah[off] = hv;
            if (split) *(us4*)&Al[off] = lv;
        }
        // stage B: 16KB/plane = 16 x 1KB wave-slices, source pre-swizzled
        #pragma unroll
        for (int i = 0; i < 4; ++i) {
            int slice = w * 4 + i;
            int p = slice * 1024 + l * 16;      // byte offset within plane
            int row = p >> 7;                   // = slice*8 + (l>>3)
            int chunk = ((p >> 4) & 7) ^ (row & 7);
            size_t src = (size_t)(ct * 128 + row) * 1024 + e0 + chunk * 8;
            gl_lds16(&Bhg[src], &Bh[slice * 512]);
            if (split) gl_lds16(&Blg[src], &Bl[slice * 512]);
        }
        __syncthreads();

        #pragma unroll
        for (int s = 0; s < 2; ++s) {
            const int slot = (s * 4 + (l >> 4)) ^ (l & 7);  // row&7 == l&7 for all frags
            bfrag af[4], alf[4], bf_[4], blf[4];
            #pragma unroll
            for (int m = 0; m < 4; ++m) {
                int row = wm * 64 + m * 16 + (l & 15);
                af[m] = *(const bfrag*)&Ah[row * 64 + slot * 8];
                if (split) alf[m] = *(const bfrag*)&Al[row * 64 + slot * 8];
            }
            #pragma unroll
            for (int n = 0; n < 4; ++n) {
                int nr = wn * 64 + n * 16 + (l & 15);
                bf_[n] = *(const bfrag*)&Bh[nr * 64 + slot * 8];
                if (split) blf[n] = *(const bfrag*)&Bl[nr * 64 + slot * 8];
            }
            #pragma unroll
            for (int m = 0; m < 4; ++m)
                #pragma unroll
                for (int n = 0; n < 4; ++n) {
                    acc[m][n] = MFMA(af[m], bf_[n], acc[m][n]);
                    if (split) {
                        acc[m][n] = MFMA(af[m], blf[n], acc[m][n]);
                        acc[m][n] = MFMA(alf[m], bf_[n], acc[m][n]);
                    }
                }
        }
    }

    if (which == 2) {
        // v: write transposed vT[(h*2+b)*64 + d][t], pack 4 consecutive t (acc r=0..3)
        #pragma unroll
        for (int m = 0; m < 4; ++m) {
            int t0g = rt * 128 + wm * 64 + m * 16 + (l >> 4) * 4;  // x-row of r=0
            int b_ = t0g >> 11, t0 = t0g & 2047;
            #pragma unroll
            for (int n = 0; n < 4; ++n) {
                int col = ct * 128 + wn * 64 + n * 16 + (l & 15);
                int h_ = col >> 6, d = col & 63;
                us4 pk;
                #pragma unroll
                for (int r = 0; r < 4; ++r) pk[r] = f2bh(acc[m][n][r]);
                *(us4*)&vT[((size_t)((h_ * 2 + b_) * 64 + d)) * 2048 + t0] = pk;
            }
        }
    } else {
        unsigned short* oh = (which == 0) ? qh : kh;
        unsigned short* ol = (which == 0) ? ql : kl;
        const float sc = (which == 0) ? QSC : 1.0f;
        #pragma unroll
        for (int m = 0; m < 4; ++m)
            #pragma unroll
            for (int r = 0; r < 4; ++r) {
                int row = rt * 128 + wm * 64 + m * 16 + (l >> 4) * 4 + r;
                #pragma unroll
                for (int n = 0; n < 4; ++n) {
                    int col = ct * 128 + wn * 64 + n * 16 + (l & 15);
                    float f = acc[m][n][r] * sc;
                    unsigned short hb = f2bh(f);
                    oh[(size_t)row * 1024 + col] = hb;
                    ol[(size_t)row * 1024 + col] = f2bh(f - bh2f(hb));
                }
            }
    }
}

// ---------------------------------------------------------------------------
// attn helpers
// ---------------------------------------------------------------------------
__device__ __forceinline__ void stage_kv(
    const unsigned short* __restrict__ kh, const unsigned short* __restrict__ kl,
    const unsigned short* __restrict__ vT,
    unsigned short* Khb, unsigned short* Klb, unsigned short* Vtb,
    int w, int l, int b, int h, int kt)
{
    #pragma unroll
    for (int i = 0; i < 2; ++i) {
        int pbase = (w * 2 + i) * 1024;    // uniform 1KB slice base (bytes)
        int p = pbase + l * 16;
        int row = p >> 7, slot = (p >> 4) & 7;
        int chunk = slot ^ (row & 7);      // inverse-swizzled source chunk
        size_t srcK = (size_t)(b * 2048 + kt * 64 + row) * 1024 + h * 64 + chunk * 8;
        size_t srcV = ((size_t)(h * 2 + b) * 64 + row) * 2048 + (size_t)kt * 64 + chunk * 8;
        gl_lds16(&kh[srcK], &Khb[pbase >> 1]);
        gl_lds16(&kl[srcK], &Klb[pbase >> 1]);
        gl_lds16(&vT[srcV], &Vtb[pbase >> 1]);
    }
}

// One 64-key flash step for one q-tile's state (split QK^T, exp2 softmax, PV).
__device__ __forceinline__ void attn_step(
    const unsigned short* Khb, const unsigned short* Klb, const unsigned short* Vtb,
    unsigned short* Pl, const bfrag* qfh, const bfrag* qfl,
    facc* O, float* mrow, float* lrow, int w, int l, bool diag)
{
    facc S[4];
    #pragma unroll
    for (int f = 0; f < 4; ++f) S[f] = (facc)(0.0f);
    #pragma unroll
    for (int s = 0; s < 2; ++s) {
        #pragma unroll
        for (int f = 0; f < 4; ++f) {
            int key = f * 16 + (l & 15);
            int ch = (s * 4 + (l >> 4)) ^ (key & 7);
            bfrag kbh = *(const bfrag*)&Khb[key * 64 + ch * 8];
            bfrag kbl = *(const bfrag*)&Klb[key * 64 + ch * 8];
            S[f] = MFMA(qfh[s], kbh, S[f]);
            S[f] = MFMA(qfh[s], kbl, S[f]);
            S[f] = MFMA(qfl[s], kbh, S[f]);
        }
    }
    if (diag) {
        #pragma unroll
        for (int f = 0; f < 4; ++f) {
            int keyl = f * 16 + (l & 15);
            #pragma unroll
            for (int r = 0; r < 4; ++r) {
                int qls = w * 16 + (l >> 4) * 4 + r;
                if (keyl > qls) S[f][r] = -1e30f;
            }
        }
    }
    #pragma unroll
    for (int r = 0; r < 4; ++r) {
        float mx = fmaxf(fmaxf(S[0][r], S[1][r]), fmaxf(S[2][r], S[3][r]));
        mx = fmaxf(mx, __shfl_xor(mx, 1));
        mx = fmaxf(mx, __shfl_xor(mx, 2));
        mx = fmaxf(mx, __shfl_xor(mx, 4));
        mx = fmaxf(mx, __shfl_xor(mx, 8));
        float mn = fmaxf(mrow[r], mx);
        float fac = EXP2(mrow[r] - mn);   // exp2 domain (q pre-scaled by log2e)
        mrow[r] = mn;
        float rs = 0.0f;
        #pragma unroll
        for (int f = 0; f < 4; ++f) { S[f][r] = EXP2(S[f][r] - mn); rs += S[f][r]; }
        rs += __shfl_xor(rs, 1); rs += __shfl_xor(rs, 2);
        rs += __shfl_xor(rs, 4); rs += __shfl_xor(rs, 8);
        lrow[r] = lrow[r] * fac + rs;
        O[0][r] *= fac; O[1][r] *= fac; O[2][r] *= fac; O[3][r] *= fac;
    }
    // P -> LDS (bf16, swizzled rows); each wave touches only its own 16 rows,
    // so no barrier needed -- same-wave ds ordering is handled by lgkmcnt.
    #pragma unroll
    for (int f = 0; f < 4; ++f) {
        int key = f * 16 + (l & 15);
        #pragma unroll
        for (int r = 0; r < 4; ++r) {
            int qr = w * 16 + (l >> 4) * 4 + r;
            Pl[qr * 64 + (((key >> 3) ^ (qr & 7)) * 8) + (key & 7)] = f2bh(S[f][r]);
        }
    }
    #pragma unroll
    for (int s = 0; s < 2; ++s) {
        int qa = w * 16 + (l & 15);
        int cha = (s * 4 + (l >> 4)) ^ (qa & 7);
        bfrag pa = *(const bfrag*)&Pl[qa * 64 + cha * 8];
        #pragma unroll
        for (int f = 0; f < 4; ++f) {
            int d = f * 16 + (l & 15);
            int chv = (s * 4 + (l >> 4)) ^ (d & 7);
            bfrag vb = *(const bfrag*)&Vtb[d * 64 + chv * 8];
            O[f] = MFMA(pa, vb, O[f]);
        }
    }
}

// ---------------------------------------------------------------------------
// attn_mfma: paired-q-tile flash attention.  grid (16, 32), block 256 (4 waves).
// Block (bx,hb) handles q-tiles {31-bx, bx}: uniform 33 steps per block.
// K/V double-buffered; prefetch stays in flight across a RAW s_barrier
// (counted-drain happens at the next __syncthreads).  2 blocks/CU exactly.
// ---------------------------------------------------------------------------
__global__ __launch_bounds__(256, 2) void attn_mfma(
    const unsigned short* __restrict__ qh, const unsigned short* __restrict__ ql,
    const unsigned short* __restrict__ kh, const unsigned short* __restrict__ kl,
    const unsigned short* __restrict__ vT, unsigned short* __restrict__ att)
{
    __shared__ unsigned short Kh[2][64 * 64], Kl[2][64 * 64], Vt[2][64 * 64], Pl[64 * 64];
    const int tid = threadIdx.x, w = tid >> 6, l = tid & 63;
    // XCD-grouping swizzle (assumes round-robin dispatch over 8 XCDs):
    // all 16 q-blocks of 4 consecutive hb land on one XCD -> K/V L2-resident.
    const int dd = blockIdx.y * 16 + blockIdx.x;
    const int xcd = dd & 7, sl = dd >> 3;
    const int hb = xcd * 4 + (sl >> 4);
    const int bx = sl & 15;
    const int qtA = 31 - bx, qtB = bx;
    const int h = hb >> 1, b = hb & 1;

    bfrag qfhA[2], qflA[2], qfhB[2], qflB[2];
    {
        const int qrowA = qtA * 64 + w * 16 + (l & 15);
        const size_t qoffA = (size_t)(b * 2048 + qrowA) * 1024 + h * 64 + (l >> 4) * 8;
        qfhA[0] = *(const bfrag*)&qh[qoffA];
        qfhA[1] = *(const bfrag*)&qh[qoffA + 32];
        qflA[0] = *(const bfrag*)&ql[qoffA];
        qflA[1] = *(const bfrag*)&ql[qoffA + 32];
        const int qrowB = qtB * 64 + w * 16 + (l & 15);
        const size_t qoffB = (size_t)(b * 2048 + qrowB) * 1024 + h * 64 + (l >> 4) * 8;
        qfhB[0] = *(const bfrag*)&qh[qoffB];
        qfhB[1] = *(const bfrag*)&qh[qoffB + 32];
        qflB[0] = *(const bfrag*)&ql[qoffB];
        qflB[1] = *(const bfrag*)&ql[qoffB + 32];
    }

    facc OA[4], OB[4];
    float mA[4], lA[4], mB[4], lB[4];
    #pragma unroll
    for (int f = 0; f < 4; ++f) { OA[f] = (facc)(0.0f); OB[f] = (facc)(0.0f); }
    #pragma unroll
    for (int r = 0; r < 4; ++r) { mA[r] = -1e30f; lA[r] = 0.0f; mB[r] = -1e30f; lB[r] = 0.0f; }

    stage_kv(kh, kl, vT, Kh[0], Kl[0], Vt[0], w, l, b, h, 0);
    int cur = 0;
    for (int kt = 0; kt <= qtA; ++kt) {
        // A: drains my previous stage (landed during prior compute) and makes
        // buf[cur^1] WAR-safe for the prefetch below.
        __syncthreads();
        if (kt < qtA)
            stage_kv(kh, kl, vT, Kh[cur ^ 1], Kl[cur ^ 1], Vt[cur ^ 1], w, l, b, h, kt + 1);
        __builtin_amdgcn_sched_barrier(0);
        // B: raw barrier, NO vmcnt -- the 6 prefetch loads stay in flight.
        // buf[cur] is complete because every wave drained it at its own A.
        __builtin_amdgcn_s_barrier();
        __builtin_amdgcn_sched_barrier(0);
        attn_step(Kh[cur], Kl[cur], Vt[cur], Pl, qfhA, qflA, OA, mA, lA, w, l, kt == qtA);
        if (kt <= qtB)
            attn_step(Kh[cur], Kl[cur], Vt[cur], Pl, qfhB, qflB, OB, mB, lB, w, l, kt == qtB);
        cur ^= 1;
    }

    #pragma unroll
    for (int f = 0; f < 4; ++f) {
        int d = h * 64 + f * 16 + (l & 15);
        #pragma unroll
        for (int r = 0; r < 4; ++r) {
            int tA = qtA * 64 + w * 16 + (l >> 4) * 4 + r;
            att[(size_t)(b * 2048 + tA) * 1024 + d] = f2bh(OA[f][r] / lA[r]);
            int tB = qtB * 64 + w * 16 + (l >> 4) * 4 + r;
            att[(size_t)(b * 2048 + tB) * 1024 + d] = f2bh(OB[f][r] / lB[r]);
        }
    }
}

// ---------------------------------------------------------------------------
// outproj: out[4096,1024] = att @ Wo^T, bf16 MFMA, fp32 out.  grid (32, 8).
// BK=64 swizzled tiles (same scheme as qkv_gemm): conflict-free ds_read_b128.
// ---------------------------------------------------------------------------
__global__ __launch_bounds__(256) void outproj(
    const unsigned short* __restrict__ att, const unsigned short* __restrict__ WoB,
    float* __restrict__ out)
{
    __shared__ unsigned short Ab[128 * 64], Bb[128 * 64];
    const int tid = threadIdx.x, w = tid >> 6, l = tid & 63;
    const int wm = w >> 1, wn = w & 1;
    const int rt = blockIdx.x, ct = blockIdx.y;

    facc acc[4][4];
    #pragma unroll
    for (int i = 0; i < 4; ++i)
        #pragma unroll
        for (int j = 0; j < 4; ++j) acc[i][j] = (facc)(0.0f);

    for (int e0 = 0; e0 < 1024; e0 += 64) {
        __syncthreads();
        #pragma unroll
        for (int i = 0; i < 4; ++i) {
            int slice = w * 4 + i;
            int p = slice * 1024 + l * 16;
            int row = p >> 7;
            int chunk = ((p >> 4) & 7) ^ (row & 7);
            gl_lds16(&att[(size_t)(rt * 128 + row) * 1024 + e0 + chunk * 8], &Ab[slice * 512]);
            gl_lds16(&WoB[(size_t)(ct * 128 + row) * 1024 + e0 + chunk * 8], &Bb[slice * 512]);
        }
        __syncthreads();
        #pragma unroll
        for (int s = 0; s < 2; ++s) {
            const int slot = (s * 4 + (l >> 4)) ^ (l & 7);
            bfrag af[4], bf_[4];
            #pragma unroll
            for (int m = 0; m < 4; ++m)
                af[m] = *(const bfrag*)&Ab[(wm * 64 + m * 16 + (l & 15)) * 64 + slot * 8];
            #pragma unroll
            for (int n = 0; n < 4; ++n)
                bf_[n] = *(const bfrag*)&Bb[(wn * 64 + n * 16 + (l & 15)) * 64 + slot * 8];
            #pragma unroll
            for (int m = 0; m < 4; ++m)
                #pragma unroll
                for (int n = 0; n < 4; ++n)
                    acc[m][n] = MFMA(af[m], bf_[n], acc[m][n]);
        }
    }
    #pragma unroll
    for (int m = 0; m < 4; ++m)
        #pragma unroll
        for (int r = 0; r < 4; ++r) {
            int row = rt * 128 + wm * 64 + m * 16 + (l >> 4) * 4 + r;
            #pragma unroll
            for (int n = 0; n < 4; ++n) {
                int col = ct * 128 + wn * 64 + n * 16 + (l & 15);
                out[(size_t)row * 1024 + col] = acc[m][n][r];
            }
        }
}

// ---------------------------------------------------------------------------
extern "C" void kernel_launch(void* const* d_in, const int* in_sizes, int n_in,
                              void* d_out, int out_size, void* d_ws, size_t ws_size,
                              hipStream_t stream) {
    const float* x  = (const float*)d_in[0];
    // d_in[1]: causal mask (applied analytically)
    const float* Wq = (const float*)d_in[2];
    const float* Wk = (const float*)d_in[3];
    const float* Wv = (const float*)d_in[4];
    const float* Wo = (const float*)d_in[5];

    uint8_t* wsb = (uint8_t*)d_ws;
    const size_t MB = 1024 * 1024;
    unsigned short* WqTh = (unsigned short*)(wsb + 0 * MB);   // [1024 n][1024 e] bf16
    unsigned short* WqTl = (unsigned short*)(wsb + 2 * MB);
    unsigned short* WkTh = (unsigned short*)(wsb + 4 * MB);
    unsigned short* WkTl = (unsigned short*)(wsb + 6 * MB);
    unsigned short* WvT  = (unsigned short*)(wsb + 8 * MB);
    unsigned short* WoB  = (unsigned short*)(wsb + 10 * MB);  // [1024 o][1024 i] bf16
    unsigned short* qh   = (unsigned short*)(wsb + 12 * MB);  // [4096][1024] bf16
    unsigned short* ql   = (unsigned short*)(wsb + 20 * MB);
    unsigned short* kh   = (unsigned short*)(wsb + 28 * MB);
    unsigned short* kl   = (unsigned short*)(wsb + 36 * MB);
    unsigned short* vT   = (unsigned short*)(wsb + 44 * MB);  // [2048 hd][2048 t] bf16
    unsigned short* att  = (unsigned short*)(wsb + 52 * MB);  // [4096][1024] bf16

    prep_w<<<dim3(16, 16, 3), 256, 0, stream>>>(Wq, Wk, Wv, WqTh, WqTl, WkTh, WkTl, WvT);
    wo_conv<<<dim3(1024), 256, 0, stream>>>(Wo, WoB);
    qkv_gemm<<<dim3(32, 8, 3), 256, 0, stream>>>(x, WqTh, WqTl, WkTh, WkTl, WvT,
                                                 qh, ql, kh, kl, vT);
    attn_mfma<<<dim3(16, 32), 256, 0, stream>>>(qh, ql, kh, kl, vT, att);
    outproj<<<dim3(32, 8), 256, 0, stream>>>(att, WoB, (float*)d_out);
}

// Round 6
// 191.994 us; speedup vs baseline: 1.3249x; 1.3249x over previous
//
#include <hip/hip_runtime.h>
#include <hip/hip_fp8.h>
#include <stdint.h>

// (B,T,E,H,D) = (2,2048,1024,16,64)
constexpr float INV_SCALE = 0.022097086912079608f;  // 1/sqrt(2048)
constexpr float LOG2E = 1.4426950408889634f;
constexpr float QSC = INV_SCALE * LOG2E;            // q pre-scale: softmax in exp2 domain

typedef __attribute__((ext_vector_type(8))) short bfrag;          // 8 bf16 (4 VGPR) MFMA frag
typedef __attribute__((ext_vector_type(4))) float facc;           // 4 f32 MFMA acc
typedef __attribute__((ext_vector_type(4))) unsigned short us4;   // 4 bf16 = 8B

#define MFMA(a, b, c) __builtin_amdgcn_mfma_f32_16x16x32_bf16((a), (b), (c), 0, 0, 0)
#define EXP2(x) __builtin_amdgcn_exp2f(x)

__device__ __forceinline__ unsigned short f2bh(float f) {        // f32 -> bf16 RNE
    union { float f; unsigned int u; } cv; cv.f = f;
    unsigned int u = cv.u;
    u += 0x7FFFu + ((u >> 16) & 1u);
    return (unsigned short)(u >> 16);
}
__device__ __forceinline__ float bh2f(unsigned short h) {
    union { unsigned int u; float f; } cv; cv.u = ((unsigned int)h) << 16;
    return cv.f;
}
__device__ __forceinline__ void gl_lds16(const unsigned short* g, unsigned short* lds) {
    // async 16B/lane global->LDS; dst is wave-uniform base, lane i lands at dst+16*i
    __builtin_amdgcn_global_load_lds(
        (const __attribute__((address_space(1))) unsigned int*)g,
        (__attribute__((address_space(3))) unsigned int*)lds, 16, 0, 0);
}
// 8 fp8(e4m3, x256) bytes -> bf16 frag (undo the 256x scale)
__device__ __forceinline__ bfrag f8frag(uint2 raw) {
    union { uint2 u; unsigned char b[8]; } cv; cv.u = raw;
    bfrag r;
    #pragma unroll
    for (int j = 0; j < 8; ++j) {
        const __hip_fp8_e4m3* t = reinterpret_cast<const __hip_fp8_e4m3*>(&cv.b[j]);
        r[j] = (short)f2bh((float)(*t) * 0.00390625f);
    }
    return r;
}

// ---------------------------------------------------------------------------
// x_split: x fp32 [4096][1024] -> xh, xl bf16 planes (hi + residual).
// ---------------------------------------------------------------------------
__global__ __launch_bounds__(256) void x_split(const float* __restrict__ x,
                                               unsigned short* __restrict__ xh,
                                               unsigned short* __restrict__ xl) {
    int idx = blockIdx.x * 256 + threadIdx.x;   // f4 index, 1,048,576 total
    facc v = *(const facc*)&x[(size_t)idx * 4];
    us4 hv, lv;
    #pragma unroll
    for (int j = 0; j < 4; ++j) {
        unsigned short hb = f2bh(v[j]);
        hv[j] = hb;
        lv[j] = f2bh(v[j] - bh2f(hb));
    }
    *(us4*)&xh[(size_t)idx * 4] = hv;
    *(us4*)&xl[(size_t)idx * 4] = lv;
}

// ---------------------------------------------------------------------------
// prep_w: per head, transpose W[h][1024 e][64 i] -> WT[h*64+i][1024 e] with
// hi/lo bf16 split for Wq/Wk, hi-only for Wv.  grid (16,16,3), block 256.
// ---------------------------------------------------------------------------
__global__ __launch_bounds__(256) void prep_w(
    const float* __restrict__ Wq, const float* __restrict__ Wk, const float* __restrict__ Wv,
    unsigned short* __restrict__ WqTh, unsigned short* __restrict__ WqTl,
    unsigned short* __restrict__ WkTh, unsigned short* __restrict__ WkTl,
    unsigned short* __restrict__ WvT)
{
    __shared__ float tile[64][65];
    const int tid = threadIdx.x;
    const int et = blockIdx.x, h = blockIdx.y, m = blockIdx.z;
    const float* W = (m == 0) ? Wq : (m == 1) ? Wk : Wv;
    #pragma unroll
    for (int rep = 0; rep < 4; ++rep) {
        int idx = rep * 256 + tid;            // f4 idx over [64e][16 i4]
        int e = idx >> 4, i4 = (idx & 15) * 4;
        facc v = *(const facc*)&W[(size_t)h * 65536 + (size_t)(et * 64 + e) * 64 + i4];
        tile[e][i4] = v.x; tile[e][i4 + 1] = v.y; tile[e][i4 + 2] = v.z; tile[e][i4 + 3] = v.w;
    }
    __syncthreads();
    unsigned short* Oh = (m == 0) ? WqTh : (m == 1) ? WkTh : WvT;
    unsigned short* Ol = (m == 0) ? WqTl : WkTl;   // unused when m==2
    #pragma unroll
    for (int rep = 0; rep < 4; ++rep) {
        int idx = rep * 256 + tid;            // [64 i][16 e4]
        int i = idx >> 4, e4 = (idx & 15) * 4;
        us4 hv, lv;
        #pragma unroll
        for (int j = 0; j < 4; ++j) {
            float f = tile[e4 + j][i];
            unsigned short hb = f2bh(f);
            hv[j] = hb;
            lv[j] = f2bh(f - bh2f(hb));
        }
        size_t o = (size_t)(h * 64 + i) * 1024 + et * 64 + e4;
        *(us4*)&Oh[o] = hv;
        if (m < 2) *(us4*)&Ol[o] = lv;
    }
}

// Wo [1024 o][1024 i] fp32 -> bf16 (already B^T layout for out = att @ Wo^T)
__global__ __launch_bounds__(256) void wo_conv(const float* __restrict__ Wo,
                                               unsigned short* __restrict__ WoB) {
    int idx = blockIdx.x * 256 + threadIdx.x;   // f4 index, 262144 total
    facc v = *(const facc*)&Wo[(size_t)idx * 4];
    us4 o;
    #pragma unroll
    for (int j = 0; j < 4; ++j) o[j] = f2bh(v[j]);
    *(us4*)&WoB[(size_t)idx * 4] = o;
}

// ---------------------------------------------------------------------------
// qkv_gemm: C[4096,1024] = X @ W per which.  128x128 tile, BK=32, 4 waves.
// LDS rows are 128B = [hi 32k | lo 32k] with XOR-8 chunk swizzle -> all
// ds_read_b128 2-way (free).  A and B both staged via global_load_lds from
// pre-split planes (per-lane source select hi/lo + inverse swizzle); zero
// conversion VALU in the loop.  Double-buffered: prefetch issued before a raw
// s_barrier, drained by next __syncthreads (attn-proven pattern).
// grid (32, 8, 3), block 256, 64KB LDS -> 2 blocks/CU.
// ---------------------------------------------------------------------------
__global__ __launch_bounds__(256, 2) void qkv_gemm(
    const unsigned short* __restrict__ xh, const unsigned short* __restrict__ xl,
    const unsigned short* __restrict__ WqTh, const unsigned short* __restrict__ WqTl,
    const unsigned short* __restrict__ WkTh, const unsigned short* __restrict__ WkTl,
    const unsigned short* __restrict__ WvT,
    unsigned short* __restrict__ qh, unsigned char* __restrict__ ql8,
    unsigned short* __restrict__ kh, unsigned short* __restrict__ kl,
    unsigned short* __restrict__ vT)
{
    __shared__ unsigned short Ac[2][128 * 64], Bc[2][128 * 64];
    const int tid = threadIdx.x;
    const int w = tid >> 6, l = tid & 63;
    const int wm = w >> 1, wn = w & 1;
    const int rt = blockIdx.x, ct = blockIdx.y, which = blockIdx.z;
    const bool split = (which < 2);
    const unsigned short* Bhg = (which == 0) ? WqTh : (which == 1) ? WkTh : WvT;
    const unsigned short* Blg = (which == 0) ? WqTl : (which == 1) ? WkTl : WvT;

    // per-lane staging geometry (constant across steps)
    const int lc = (l & 7) ^ (l >> 3);          // logical chunk at this lane's dest
    const int krel = (lc & 3) * 8;              // k-offset within BK=32
    const unsigned short* Ag = (lc < 4) ? xh : xl;
    const unsigned short* Bg = (lc < 4) ? Bhg : Blg;

    facc acc[4][4];
    #pragma unroll
    for (int i = 0; i < 4; ++i)
        #pragma unroll
        for (int j = 0; j < 4; ++j) acc[i][j] = (facc)(0.0f);

    // ---- stage one BK=32 tile pair into buffer `buf` from k-offset e0 ----
    auto stage = [&](int buf, int e0) {
        #pragma unroll
        for (int i = 0; i < 4; ++i) {
            int slice = w * 4 + i;
            int row = slice * 8 + (l >> 3);
            gl_lds16(&Ag[(size_t)(rt * 128 + row) * 1024 + e0 + krel], &Ac[buf][slice * 512]);
            gl_lds16(&Bg[(size_t)(ct * 128 + row) * 1024 + e0 + krel], &Bc[buf][slice * 512]);
        }
    };

    stage(0, 0);
    int cur = 0;
    for (int t = 0; t < 32; ++t) {
        __syncthreads();                         // drain: buf[cur] fully landed (all waves)
        if (t < 31) stage(cur ^ 1, (t + 1) * 32);
        __builtin_amdgcn_sched_barrier(0);
        __builtin_amdgcn_s_barrier();            // raw: prefetch stays in flight
        __builtin_amdgcn_sched_barrier(0);

        const int ca = (l >> 4) ^ (l & 7);       // physical chunk of hi frag
        const int cb = ca ^ 4;                   // physical chunk of lo frag
        bfrag af[4], alf[4], bf_[4], blf[4];
        #pragma unroll
        for (int m = 0; m < 4; ++m) {
            int row = wm * 64 + m * 16 + (l & 15);
            af[m] = *(const bfrag*)&Ac[cur][row * 64 + ca * 8];
            if (split) alf[m] = *(const bfrag*)&Ac[cur][row * 64 + cb * 8];
        }
        #pragma unroll
        for (int n = 0; n < 4; ++n) {
            int nr = wn * 64 + n * 16 + (l & 15);
            bf_[n] = *(const bfrag*)&Bc[cur][nr * 64 + ca * 8];
            if (split) blf[n] = *(const bfrag*)&Bc[cur][nr * 64 + cb * 8];
        }
        #pragma unroll
        for (int m = 0; m < 4; ++m)
            #pragma unroll
            for (int n = 0; n < 4; ++n) {
                acc[m][n] = MFMA(af[m], bf_[n], acc[m][n]);
                if (split) {
                    acc[m][n] = MFMA(af[m], blf[n], acc[m][n]);
                    acc[m][n] = MFMA(alf[m], bf_[n], acc[m][n]);
                }
            }
        cur ^= 1;
    }

    if (which == 2) {
        // v: write transposed vT[(h*2+b)*64 + d][t], pack 4 consecutive t (acc r=0..3)
        #pragma unroll
        for (int m = 0; m < 4; ++m) {
            int t0g = rt * 128 + wm * 64 + m * 16 + (l >> 4) * 4;  // x-row of r=0
            int b_ = t0g >> 11, t0 = t0g & 2047;
            #pragma unroll
            for (int n = 0; n < 4; ++n) {
                int col = ct * 128 + wn * 64 + n * 16 + (l & 15);
                int h_ = col >> 6, d = col & 63;
                us4 pk;
                #pragma unroll
                for (int r = 0; r < 4; ++r) pk[r] = f2bh(acc[m][n][r]);
                *(us4*)&vT[((size_t)((h_ * 2 + b_) * 64 + d)) * 2048 + t0] = pk;
            }
        }
    } else if (which == 1) {
        #pragma unroll
        for (int m = 0; m < 4; ++m)
            #pragma unroll
            for (int r = 0; r < 4; ++r) {
                int row = rt * 128 + wm * 64 + m * 16 + (l >> 4) * 4 + r;
                #pragma unroll
                for (int n = 0; n < 4; ++n) {
                    int col = ct * 128 + wn * 64 + n * 16 + (l & 15);
                    float f = acc[m][n][r];
                    unsigned short hb = f2bh(f);
                    kh[(size_t)row * 1024 + col] = hb;
                    kl[(size_t)row * 1024 + col] = f2bh(f - bh2f(hb));
                }
            }
    } else {
        // q: hi bf16 + lo as fp8 e4m3 scaled by 256 (lo values ~1e-3 after QSC)
        #pragma unroll
        for (int m = 0; m < 4; ++m)
            #pragma unroll
            for (int r = 0; r < 4; ++r) {
                int row = rt * 128 + wm * 64 + m * 16 + (l >> 4) * 4 + r;
                #pragma unroll
                for (int n = 0; n < 4; ++n) {
                    int col = ct * 128 + wn * 64 + n * 16 + (l & 15);
                    float f = acc[m][n][r] * QSC;
                    unsigned short hb = f2bh(f);
                    qh[(size_t)row * 1024 + col] = hb;
                    __hip_fp8_e4m3 e((f - bh2f(hb)) * 256.0f);
                    ql8[(size_t)row * 1024 + col] = *reinterpret_cast<unsigned char*>(&e);
                }
            }
    }
}

// ---------------------------------------------------------------------------
// attn helpers
// ---------------------------------------------------------------------------
__device__ __forceinline__ void stage_kv(
    const unsigned short* __restrict__ kh, const unsigned short* __restrict__ kl,
    const unsigned short* __restrict__ vT,
    unsigned short* Khb, unsigned short* Klb, unsigned short* Vtb,
    int w, int l, int b, int h, int kt)
{
    #pragma unroll
    for (int i = 0; i < 2; ++i) {
        int pbase = (w * 2 + i) * 1024;    // uniform 1KB slice base (bytes)
        int p = pbase + l * 16;
        int row = p >> 7, slot = (p >> 4) & 7;
        int chunk = slot ^ (row & 7);      // inverse-swizzled source chunk
        size_t srcK = (size_t)(b * 2048 + kt * 64 + row) * 1024 + h * 64 + chunk * 8;
        size_t srcV = ((size_t)(h * 2 + b) * 64 + row) * 2048 + (size_t)kt * 64 + chunk * 8;
        gl_lds16(&kh[srcK], &Khb[pbase >> 1]);
        gl_lds16(&kl[srcK], &Klb[pbase >> 1]);
        gl_lds16(&vT[srcV], &Vtb[pbase >> 1]);
    }
}

// One 64-key flash step for one q-tile's state (split QK^T, exp2 softmax, PV).
__device__ __forceinline__ void attn_step(
    const unsigned short* Khb, const unsigned short* Klb, const unsigned short* Vtb,
    unsigned short* Pl, const bfrag* qfh, const bfrag* qfl,
    facc* O, float* mrow, float* lrow, int w, int l, bool diag)
{
    facc S[4];
    #pragma unroll
    for (int f = 0; f < 4; ++f) S[f] = (facc)(0.0f);
    #pragma unroll
    for (int s = 0; s < 2; ++s) {
        #pragma unroll
        for (int f = 0; f < 4; ++f) {
            int key = f * 16 + (l & 15);
            int ch = (s * 4 + (l >> 4)) ^ (key & 7);
            bfrag kbh = *(const bfrag*)&Khb[key * 64 + ch * 8];
            bfrag kbl = *(const bfrag*)&Klb[key * 64 + ch * 8];
            S[f] = MFMA(qfh[s], kbh, S[f]);
            S[f] = MFMA(qfh[s], kbl, S[f]);
            S[f] = MFMA(qfl[s], kbh, S[f]);
        }
    }
    if (diag) {
        #pragma unroll
        for (int f = 0; f < 4; ++f) {
            int keyl = f * 16 + (l & 15);
            #pragma unroll
            for (int r = 0; r < 4; ++r) {
                int qls = w * 16 + (l >> 4) * 4 + r;
                if (keyl > qls) S[f][r] = -1e30f;
            }
        }
    }
    #pragma unroll
    for (int r = 0; r < 4; ++r) {
        float mx = fmaxf(fmaxf(S[0][r], S[1][r]), fmaxf(S[2][r], S[3][r]));
        mx = fmaxf(mx, __shfl_xor(mx, 1));
        mx = fmaxf(mx, __shfl_xor(mx, 2));
        mx = fmaxf(mx, __shfl_xor(mx, 4));
        mx = fmaxf(mx, __shfl_xor(mx, 8));
        float mn = fmaxf(mrow[r], mx);
        float fac = EXP2(mrow[r] - mn);   // exp2 domain (q pre-scaled by log2e)
        mrow[r] = mn;
        float rs = 0.0f;
        #pragma unroll
        for (int f = 0; f < 4; ++f) { S[f][r] = EXP2(S[f][r] - mn); rs += S[f][r]; }
        rs += __shfl_xor(rs, 1); rs += __shfl_xor(rs, 2);
        rs += __shfl_xor(rs, 4); rs += __shfl_xor(rs, 8);
        lrow[r] = lrow[r] * fac + rs;
        O[0][r] *= fac; O[1][r] *= fac; O[2][r] *= fac; O[3][r] *= fac;
    }
    // P -> LDS (bf16, swizzled rows); same-wave rows only, lgkmcnt orders it.
    #pragma unroll
    for (int f = 0; f < 4; ++f) {
        int key = f * 16 + (l & 15);
        #pragma unroll
        for (int r = 0; r < 4; ++r) {
            int qr = w * 16 + (l >> 4) * 4 + r;
            Pl[qr * 64 + (((key >> 3) ^ (qr & 7)) * 8) + (key & 7)] = f2bh(S[f][r]);
        }
    }
    #pragma unroll
    for (int s = 0; s < 2; ++s) {
        int qa = w * 16 + (l & 15);
        int cha = (s * 4 + (l >> 4)) ^ (qa & 7);
        bfrag pa = *(const bfrag*)&Pl[qa * 64 + cha * 8];
        #pragma unroll
        for (int f = 0; f < 4; ++f) {
            int d = f * 16 + (l & 15);
            int chv = (s * 4 + (l >> 4)) ^ (d & 7);
            bfrag vb = *(const bfrag*)&Vtb[d * 64 + chv * 8];
            O[f] = MFMA(pa, vb, O[f]);
        }
    }
}

// ---------------------------------------------------------------------------
// attn_mfma: paired-q-tile flash attention.  grid (16, 32), block 256 (4 waves).
// ---------------------------------------------------------------------------
__global__ __launch_bounds__(256, 2) void attn_mfma(
    const unsigned short* __restrict__ qh, const unsigned char* __restrict__ ql8,
    const unsigned short* __restrict__ kh, const unsigned short* __restrict__ kl,
    const unsigned short* __restrict__ vT, unsigned short* __restrict__ att)
{
    __shared__ unsigned short Kh[2][64 * 64], Kl[2][64 * 64], Vt[2][64 * 64], Pl[64 * 64];
    const int tid = threadIdx.x, w = tid >> 6, l = tid & 63;
    const int dd = blockIdx.y * 16 + blockIdx.x;
    const int xcd = dd & 7, sl = dd >> 3;
    const int hb = xcd * 4 + (sl >> 4);
    const int bx = sl & 15;
    const int qtA = 31 - bx, qtB = bx;
    const int h = hb >> 1, b = hb & 1;

    bfrag qfhA[2], qflA[2], qfhB[2], qflB[2];
    {
        const int qrowA = qtA * 64 + w * 16 + (l & 15);
        const size_t qoffA = (size_t)(b * 2048 + qrowA) * 1024 + h * 64 + (l >> 4) * 8;
        qfhA[0] = *(const bfrag*)&qh[qoffA];
        qfhA[1] = *(const bfrag*)&qh[qoffA + 32];
        qflA[0] = f8frag(*(const uint2*)&ql8[qoffA]);
        qflA[1] = f8frag(*(const uint2*)&ql8[qoffA + 32]);
        const int qrowB = qtB * 64 + w * 16 + (l & 15);
        const size_t qoffB = (size_t)(b * 2048 + qrowB) * 1024 + h * 64 + (l >> 4) * 8;
        qfhB[0] = *(const bfrag*)&qh[qoffB];
        qfhB[1] = *(const bfrag*)&qh[qoffB + 32];
        qflB[0] = f8frag(*(const uint2*)&ql8[qoffB]);
        qflB[1] = f8frag(*(const uint2*)&ql8[qoffB + 32]);
    }

    facc OA[4], OB[4];
    float mA[4], lA[4], mB[4], lB[4];
    #pragma unroll
    for (int f = 0; f < 4; ++f) { OA[f] = (facc)(0.0f); OB[f] = (facc)(0.0f); }
    #pragma unroll
    for (int r = 0; r < 4; ++r) { mA[r] = -1e30f; lA[r] = 0.0f; mB[r] = -1e30f; lB[r] = 0.0f; }

    stage_kv(kh, kl, vT, Kh[0], Kl[0], Vt[0], w, l, b, h, 0);
    int cur = 0;
    for (int kt = 0; kt <= qtA; ++kt) {
        __syncthreads();
        if (kt < qtA)
            stage_kv(kh, kl, vT, Kh[cur ^ 1], Kl[cur ^ 1], Vt[cur ^ 1], w, l, b, h, kt + 1);
        __builtin_amdgcn_sched_barrier(0);
        __builtin_amdgcn_s_barrier();
        __builtin_amdgcn_sched_barrier(0);
        attn_step(Kh[cur], Kl[cur], Vt[cur], Pl, qfhA, qflA, OA, mA, lA, w, l, kt == qtA);
        if (kt <= qtB)
            attn_step(Kh[cur], Kl[cur], Vt[cur], Pl, qfhB, qflB, OB, mB, lB, w, l, kt == qtB);
        cur ^= 1;
    }

    #pragma unroll
    for (int f = 0; f < 4; ++f) {
        int d = h * 64 + f * 16 + (l & 15);
        #pragma unroll
        for (int r = 0; r < 4; ++r) {
            int tA = qtA * 64 + w * 16 + (l >> 4) * 4 + r;
            att[(size_t)(b * 2048 + tA) * 1024 + d] = f2bh(OA[f][r] / lA[r]);
            int tB = qtB * 64 + w * 16 + (l >> 4) * 4 + r;
            att[(size_t)(b * 2048 + tB) * 1024 + d] = f2bh(OB[f][r] / lB[r]);
        }
    }
}

// ---------------------------------------------------------------------------
// outproj: out[4096,1024] = att @ Wo^T.  BK=64 swizzled, double-buffered with
// the same prefetch-across-raw-barrier loop.  grid (32, 8), 64KB LDS.
// ---------------------------------------------------------------------------
__global__ __launch_bounds__(256, 2) void outproj(
    const unsigned short* __restrict__ att, const unsigned short* __restrict__ WoB,
    float* __restrict__ out)
{
    __shared__ unsigned short Ab[2][128 * 64], Bb[2][128 * 64];
    const int tid = threadIdx.x, w = tid >> 6, l = tid & 63;
    const int wm = w >> 1, wn = w & 1;
    const int rt = blockIdx.x, ct = blockIdx.y;

    const int lc = (l & 7) ^ (l >> 3);         // logical chunk (0..7) -> k-offset lc*8
    facc acc[4][4];
    #pragma unroll
    for (int i = 0; i < 4; ++i)
        #pragma unroll
        for (int j = 0; j < 4; ++j) acc[i][j] = (facc)(0.0f);

    auto stage = [&](int buf, int e0) {
        #pragma unroll
        for (int i = 0; i < 4; ++i) {
            int slice = w * 4 + i;
            int row = slice * 8 + (l >> 3);
            gl_lds16(&att[(size_t)(rt * 128 + row) * 1024 + e0 + lc * 8], &Ab[buf][slice * 512]);
            gl_lds16(&WoB[(size_t)(ct * 128 + row) * 1024 + e0 + lc * 8], &Bb[buf][slice * 512]);
        }
    };

    stage(0, 0);
    int cur = 0;
    for (int t = 0; t < 16; ++t) {
        __syncthreads();
        if (t < 15) stage(cur ^ 1, (t + 1) * 64);
        __builtin_amdgcn_sched_barrier(0);
        __builtin_amdgcn_s_barrier();
        __builtin_amdgcn_sched_barrier(0);
        #pragma unroll
        for (int s = 0; s < 2; ++s) {
            const int slot = (s * 4 + (l >> 4)) ^ (l & 7);
            bfrag af[4], bf_[4];
            #pragma unroll
            for (int m = 0; m < 4; ++m)
                af[m] = *(const bfrag*)&Ab[cur][(wm * 64 + m * 16 + (l & 15)) * 64 + slot * 8];
            #pragma unroll
            for (int n = 0; n < 4; ++n)
                bf_[n] = *(const bfrag*)&Bb[cur][(wn * 64 + n * 16 + (l & 15)) * 64 + slot * 8];
            #pragma unroll
            for (int m = 0; m < 4; ++m)
                #pragma unroll
                for (int n = 0; n < 4; ++n)
                    acc[m][n] = MFMA(af[m], bf_[n], acc[m][n]);
        }
        cur ^= 1;
    }
    #pragma unroll
    for (int m = 0; m < 4; ++m)
        #pragma unroll
        for (int r = 0; r < 4; ++r) {
            int row = rt * 128 + wm * 64 + m * 16 + (l >> 4) * 4 + r;
            #pragma unroll
            for (int n = 0; n < 4; ++n) {
                int col = ct * 128 + wn * 64 + n * 16 + (l & 15);
                out[(size_t)row * 1024 + col] = acc[m][n][r];
            }
        }
}

// ---------------------------------------------------------------------------
extern "C" void kernel_launch(void* const* d_in, const int* in_sizes, int n_in,
                              void* d_out, int out_size, void* d_ws, size_t ws_size,
                              hipStream_t stream) {
    const float* x  = (const float*)d_in[0];
    // d_in[1]: causal mask (applied analytically)
    const float* Wq = (const float*)d_in[2];
    const float* Wk = (const float*)d_in[3];
    const float* Wv = (const float*)d_in[4];
    const float* Wo = (const float*)d_in[5];

    uint8_t* wsb = (uint8_t*)d_ws;
    const size_t MB = 1024 * 1024;
    // 64MB layout.  xh overlays att (xh dead before attn writes att).
    unsigned short* WqTh = (unsigned short*)(wsb + 0 * MB);
    unsigned short* WqTl = (unsigned short*)(wsb + 2 * MB);
    unsigned short* WkTh = (unsigned short*)(wsb + 4 * MB);
    unsigned short* WkTl = (unsigned short*)(wsb + 6 * MB);
    unsigned short* WvT  = (unsigned short*)(wsb + 8 * MB);
    unsigned short* qh   = (unsigned short*)(wsb + 10 * MB);  // 8MB
    unsigned char*  ql8  = (unsigned char*)(wsb + 18 * MB);   // 4MB fp8
    unsigned short* kh   = (unsigned short*)(wsb + 22 * MB);  // 8MB
    unsigned short* kl   = (unsigned short*)(wsb + 30 * MB);  // 8MB
    unsigned short* vT   = (unsigned short*)(wsb + 38 * MB);  // 8MB
    unsigned short* att  = (unsigned short*)(wsb + 46 * MB);  // 8MB
    unsigned short* xh   = (unsigned short*)(wsb + 46 * MB);  // 8MB (alias att)
    unsigned short* WoB  = (unsigned short*)(wsb + 54 * MB);  // 2MB
    unsigned short* xl   = (unsigned short*)(wsb + 56 * MB);  // 8MB

    x_split<<<dim3(4096), 256, 0, stream>>>(x, xh, xl);
    prep_w<<<dim3(16, 16, 3), 256, 0, stream>>>(Wq, Wk, Wv, WqTh, WqTl, WkTh, WkTl, WvT);
    wo_conv<<<dim3(1024), 256, 0, stream>>>(Wo, WoB);
    qkv_gemm<<<dim3(32, 8, 3), 256, 0, stream>>>(xh, xl, WqTh, WqTl, WkTh, WkTl, WvT,
                                                 qh, ql8, kh, kl, vT);
    attn_mfma<<<dim3(16, 32), 256, 0, stream>>>(qh, ql8, kh, kl, vT, att);
    outproj<<<dim3(32, 8), 256, 0, stream>>>(att, WoB, (float*)d_out);
}

// Round 7
// 172.863 us; speedup vs baseline: 1.4715x; 1.1107x over previous
//
#include <hip/hip_runtime.h>
#include <hip/hip_fp8.h>
#include <stdint.h>

// (B,T,E,H,D) = (2,2048,1024,16,64)
constexpr float INV_SCALE = 0.022097086912079608f;  // 1/sqrt(2048)
constexpr float LOG2E = 1.4426950408889634f;
constexpr float QSC = INV_SCALE * LOG2E;            // q pre-scale: softmax in exp2 domain

typedef __attribute__((ext_vector_type(8))) short bfrag;          // 8 bf16 (4 VGPR) MFMA frag
typedef __attribute__((ext_vector_type(4))) float facc;           // 4 f32 MFMA acc
typedef __attribute__((ext_vector_type(4))) unsigned short us4;   // 4 bf16 = 8B

#define MFMA(a, b, c) __builtin_amdgcn_mfma_f32_16x16x32_bf16((a), (b), (c), 0, 0, 0)
#define EXP2(x) __builtin_amdgcn_exp2f(x)

__device__ __forceinline__ unsigned short f2bh(float f) {        // f32 -> bf16 RNE
    union { float f; unsigned int u; } cv; cv.f = f;
    unsigned int u = cv.u;
    u += 0x7FFFu + ((u >> 16) & 1u);
    return (unsigned short)(u >> 16);
}
__device__ __forceinline__ float bh2f(unsigned short h) {
    union { unsigned int u; float f; } cv; cv.u = ((unsigned int)h) << 16;
    return cv.f;
}
__device__ __forceinline__ void gl_lds16(const unsigned short* g, unsigned short* lds) {
    // async 16B/lane global->LDS; dst is wave-uniform base, lane i lands at dst+16*i
    __builtin_amdgcn_global_load_lds(
        (const __attribute__((address_space(1))) unsigned int*)g,
        (__attribute__((address_space(3))) unsigned int*)lds, 16, 0, 0);
}
// 8 fp8(e4m3, x256) bytes -> bf16 frag (undo the 256x scale)
__device__ __forceinline__ bfrag f8frag(uint2 raw) {
    union { uint2 u; unsigned char b[8]; } cv; cv.u = raw;
    bfrag r;
    #pragma unroll
    for (int j = 0; j < 8; ++j) {
        const __hip_fp8_e4m3* t = reinterpret_cast<const __hip_fp8_e4m3*>(&cv.b[j]);
        r[j] = (short)f2bh((float)(*t) * 0.00390625f);
    }
    return r;
}

// ---------------------------------------------------------------------------
// x_split: x fp32 [4096][1024] -> xh, xl bf16 planes (hi + residual).
// ---------------------------------------------------------------------------
__global__ __launch_bounds__(256) void x_split(const float* __restrict__ x,
                                               unsigned short* __restrict__ xh,
                                               unsigned short* __restrict__ xl) {
    int idx = blockIdx.x * 256 + threadIdx.x;   // f4 index, 1,048,576 total
    facc v = *(const facc*)&x[(size_t)idx * 4];
    us4 hv, lv;
    #pragma unroll
    for (int j = 0; j < 4; ++j) {
        unsigned short hb = f2bh(v[j]);
        hv[j] = hb;
        lv[j] = f2bh(v[j] - bh2f(hb));
    }
    *(us4*)&xh[(size_t)idx * 4] = hv;
    *(us4*)&xl[(size_t)idx * 4] = lv;
}

// ---------------------------------------------------------------------------
// prep_w: per head, transpose W[h][1024 e][64 i] -> WT[h*64+i][1024 e] with
// hi/lo bf16 split for Wq/Wk, hi-only for Wv.  grid (16,16,3), block 256.
// ---------------------------------------------------------------------------
__global__ __launch_bounds__(256) void prep_w(
    const float* __restrict__ Wq, const float* __restrict__ Wk, const float* __restrict__ Wv,
    unsigned short* __restrict__ WqTh, unsigned short* __restrict__ WqTl,
    unsigned short* __restrict__ WkTh, unsigned short* __restrict__ WkTl,
    unsigned short* __restrict__ WvT)
{
    __shared__ float tile[64][65];
    const int tid = threadIdx.x;
    const int et = blockIdx.x, h = blockIdx.y, m = blockIdx.z;
    const float* W = (m == 0) ? Wq : (m == 1) ? Wk : Wv;
    #pragma unroll
    for (int rep = 0; rep < 4; ++rep) {
        int idx = rep * 256 + tid;            // f4 idx over [64e][16 i4]
        int e = idx >> 4, i4 = (idx & 15) * 4;
        facc v = *(const facc*)&W[(size_t)h * 65536 + (size_t)(et * 64 + e) * 64 + i4];
        tile[e][i4] = v.x; tile[e][i4 + 1] = v.y; tile[e][i4 + 2] = v.z; tile[e][i4 + 3] = v.w;
    }
    __syncthreads();
    unsigned short* Oh = (m == 0) ? WqTh : (m == 1) ? WkTh : WvT;
    unsigned short* Ol = (m == 0) ? WqTl : WkTl;   // unused when m==2
    #pragma unroll
    for (int rep = 0; rep < 4; ++rep) {
        int idx = rep * 256 + tid;            // [64 i][16 e4]
        int i = idx >> 4, e4 = (idx & 15) * 4;
        us4 hv, lv;
        #pragma unroll
        for (int j = 0; j < 4; ++j) {
            float f = tile[e4 + j][i];
            unsigned short hb = f2bh(f);
            hv[j] = hb;
            lv[j] = f2bh(f - bh2f(hb));
        }
        size_t o = (size_t)(h * 64 + i) * 1024 + et * 64 + e4;
        *(us4*)&Oh[o] = hv;
        if (m < 2) *(us4*)&Ol[o] = lv;
    }
}

// Wo [1024 o][1024 i] fp32 -> bf16 (already B^T layout for out = att @ Wo^T)
__global__ __launch_bounds__(256) void wo_conv(const float* __restrict__ Wo,
                                               unsigned short* __restrict__ WoB) {
    int idx = blockIdx.x * 256 + threadIdx.x;   // f4 index, 262144 total
    facc v = *(const facc*)&Wo[(size_t)idx * 4];
    us4 o;
    #pragma unroll
    for (int j = 0; j < 4; ++j) o[j] = f2bh(v[j]);
    *(us4*)&WoB[(size_t)idx * 4] = o;
}

// ---------------------------------------------------------------------------
// qkv_fused: for block (ct, rt): compute q,k,v for rows [rt*128,+128) and
// cols [ct*128,+128) in ONE pass over K=1024.  8 waves (2x4), per-wave 64x32
// per output.  A(x hi/lo) staged once and reused by q,k,v.  LDS 128KB dyn:
// A,Bq,Bk: [2][128 rows][64] (hi|lo packed, XOR-8 swizzle); Bv: [2][128][64]
// (two BK=32 windows per row).  Counted-vmcnt pipeline: raw barrier -> issue
// next stage (7 loads/wave) -> s_waitcnt vmcnt(7) -> raw barrier -> compute.
// grid (8 ct, 32 rt) = 256 blocks = 1/CU, no tail; same-ct blocks share XCD
// (weights L2-resident).
// ---------------------------------------------------------------------------
__global__ __launch_bounds__(512, 2) void qkv_fused(
    const unsigned short* __restrict__ xh, const unsigned short* __restrict__ xl,
    const unsigned short* __restrict__ WqTh, const unsigned short* __restrict__ WqTl,
    const unsigned short* __restrict__ WkTh, const unsigned short* __restrict__ WkTl,
    const unsigned short* __restrict__ WvT,
    unsigned short* __restrict__ qh, unsigned char* __restrict__ ql8,
    unsigned short* __restrict__ kh, unsigned short* __restrict__ kl,
    unsigned short* __restrict__ vT)
{
    extern __shared__ unsigned short sm[];
    unsigned short* Ab = sm;               // [2][128*64] 32KB
    unsigned short* Qb = sm + 16384;       // 32KB
    unsigned short* Kb = sm + 32768;       // 32KB
    unsigned short* Vb = sm + 49152;       // 32KB
    const int tid = threadIdx.x;
    const int w = tid >> 6, l = tid & 63;
    const int wm = w >> 2, wn = w & 3;     // 2 x 4 wave grid
    const int ct = blockIdx.x, rt = blockIdx.y;

    // staging geometry (constant): dest slot (l&7) of row (l>>3) within slice
    // holds logical chunk lc; lc>>2 selects hi/lo plane, (lc&3)*8 = k-offset.
    const int lc = (l & 7) ^ (l >> 3);
    const int krel = (lc & 3) * 8;
    const unsigned short* Axp = (lc < 4) ? xh : xl;
    const unsigned short* Qp  = (lc < 4) ? WqTh : WqTl;
    const unsigned short* Kp  = (lc < 4) ? WkTh : WkTl;

    facc accq[4][2], acck[4][2], accv[4][2];
    #pragma unroll
    for (int m = 0; m < 4; ++m)
        #pragma unroll
        for (int n = 0; n < 2; ++n) {
            accq[m][n] = (facc)(0.0f); acck[m][n] = (facc)(0.0f); accv[m][n] = (facc)(0.0f);
        }

    auto stageAB = [&](int buf, int e0) {
        #pragma unroll
        for (int i = 0; i < 2; ++i) {
            int slice = w * 2 + i;                   // 0..15
            int row = slice * 8 + (l >> 3);
            size_t sa = (size_t)(rt * 128 + row) * 1024 + e0 + krel;
            size_t sb = (size_t)(ct * 128 + row) * 1024 + e0 + krel;
            gl_lds16(&Axp[sa], &Ab[buf * 8192 + slice * 512]);
            gl_lds16(&Qp[sb],  &Qb[buf * 8192 + slice * 512]);
            gl_lds16(&Kp[sb],  &Kb[buf * 8192 + slice * 512]);
        }
    };

    // prologue: window 0 of A/Bq/Bk + full v window 0
    stageAB(0, 0);
    #pragma unroll
    for (int i = 0; i < 2; ++i) {
        int slice = w * 2 + i;
        int row = slice * 8 + (l >> 3);
        gl_lds16(&WvT[(size_t)(ct * 128 + row) * 1024 + lc * 8], &Vb[slice * 512]);
    }
    asm volatile("s_waitcnt vmcnt(0)" ::: "memory");
    __builtin_amdgcn_s_barrier();

    for (int t = 0; t < 32; ++t) {
        __builtin_amdgcn_s_barrier();              // bar1: all done with t-1 compute
        __builtin_amdgcn_sched_barrier(0);
        if (t < 31) stageAB((t + 1) & 1, (t + 1) * 32);      // 6 loads/wave
        {   // half of v window (t>>1)+1 : 1 load/wave (t <= 29)
            int wv = (t >> 1) + 1;
            if (wv < 16) {
                int slice = w + (t & 1) * 8;
                int row = slice * 8 + (l >> 3);
                gl_lds16(&WvT[(size_t)(ct * 128 + row) * 1024 + wv * 64 + lc * 8],
                         &Vb[(wv & 1) * 8192 + slice * 512]);
            }
        }
        __builtin_amdgcn_sched_barrier(0);
        if (t < 30)       asm volatile("s_waitcnt vmcnt(7)" ::: "memory");
        else if (t == 30) asm volatile("s_waitcnt vmcnt(6)" ::: "memory");
        else              asm volatile("s_waitcnt vmcnt(0)" ::: "memory");
        __builtin_amdgcn_sched_barrier(0);
        __builtin_amdgcn_s_barrier();              // bar2: everyone's cur loads landed
        __builtin_amdgcn_sched_barrier(0);

        const unsigned short* Ac = &Ab[(t & 1) * 8192];
        const unsigned short* Qc = &Qb[(t & 1) * 8192];
        const unsigned short* Kc = &Kb[(t & 1) * 8192];
        const unsigned short* Vc = &Vb[((t >> 1) & 1) * 8192];
        const int ca = (l >> 4) ^ (l & 7);         // phys chunk of hi frag
        const int cb = ca ^ 4;                     // lo frag
        const int cv = ca ^ ((t & 1) << 2);        // v frag (window parity)

        bfrag afh[4], afl[4];
        #pragma unroll
        for (int m = 0; m < 4; ++m) {
            int row = wm * 64 + m * 16 + (l & 15);
            afh[m] = *(const bfrag*)&Ac[row * 64 + ca * 8];
            afl[m] = *(const bfrag*)&Ac[row * 64 + cb * 8];
        }
        #pragma unroll
        for (int n = 0; n < 2; ++n) {
            int nr = wn * 32 + n * 16 + (l & 15);
            bfrag bv = *(const bfrag*)&Vc[nr * 64 + cv * 8];
            #pragma unroll
            for (int m = 0; m < 4; ++m) accv[m][n] = MFMA(afh[m], bv, accv[m][n]);
        }
        #pragma unroll
        for (int n = 0; n < 2; ++n) {
            int nr = wn * 32 + n * 16 + (l & 15);
            bfrag bh = *(const bfrag*)&Qc[nr * 64 + ca * 8];
            bfrag bl = *(const bfrag*)&Qc[nr * 64 + cb * 8];
            #pragma unroll
            for (int m = 0; m < 4; ++m) {
                accq[m][n] = MFMA(afh[m], bh, accq[m][n]);
                accq[m][n] = MFMA(afh[m], bl, accq[m][n]);
                accq[m][n] = MFMA(afl[m], bh, accq[m][n]);
            }
        }
        #pragma unroll
        for (int n = 0; n < 2; ++n) {
            int nr = wn * 32 + n * 16 + (l & 15);
            bfrag bh = *(const bfrag*)&Kc[nr * 64 + ca * 8];
            bfrag bl = *(const bfrag*)&Kc[nr * 64 + cb * 8];
            #pragma unroll
            for (int m = 0; m < 4; ++m) {
                acck[m][n] = MFMA(afh[m], bh, acck[m][n]);
                acck[m][n] = MFMA(afh[m], bl, acck[m][n]);
                acck[m][n] = MFMA(afl[m], bh, acck[m][n]);
            }
        }
    }

    // epilogue
    #pragma unroll
    for (int m = 0; m < 4; ++m)
        #pragma unroll
        for (int r = 0; r < 4; ++r) {
            int row = rt * 128 + wm * 64 + m * 16 + (l >> 4) * 4 + r;
            #pragma unroll
            for (int n = 0; n < 2; ++n) {
                int col = ct * 128 + wn * 32 + n * 16 + (l & 15);
                float fq = accq[m][n][r] * QSC;
                unsigned short hb = f2bh(fq);
                qh[(size_t)row * 1024 + col] = hb;
                __hip_fp8_e4m3 e((fq - bh2f(hb)) * 256.0f);
                ql8[(size_t)row * 1024 + col] = *reinterpret_cast<unsigned char*>(&e);
                float fk = acck[m][n][r];
                unsigned short kb = f2bh(fk);
                kh[(size_t)row * 1024 + col] = kb;
                kl[(size_t)row * 1024 + col] = f2bh(fk - bh2f(kb));
            }
        }
    #pragma unroll
    for (int m = 0; m < 4; ++m) {
        int t0g = rt * 128 + wm * 64 + m * 16 + (l >> 4) * 4;
        int b_ = t0g >> 11, t0 = t0g & 2047;
        #pragma unroll
        for (int n = 0; n < 2; ++n) {
            int col = ct * 128 + wn * 32 + n * 16 + (l & 15);
            int h_ = col >> 6, d = col & 63;
            us4 pk;
            #pragma unroll
            for (int r = 0; r < 4; ++r) pk[r] = f2bh(accv[m][n][r]);
            *(us4*)&vT[((size_t)((h_ * 2 + b_) * 64 + d)) * 2048 + t0] = pk;
        }
    }
}

// ---------------------------------------------------------------------------
// attn helpers
// ---------------------------------------------------------------------------
__device__ __forceinline__ void stage_kv(
    const unsigned short* __restrict__ kh, const unsigned short* __restrict__ kl,
    const unsigned short* __restrict__ vT,
    unsigned short* Khb, unsigned short* Klb, unsigned short* Vtb,
    int w, int l, int b, int h, int kt)
{
    #pragma unroll
    for (int i = 0; i < 2; ++i) {
        int pbase = (w * 2 + i) * 1024;    // uniform 1KB slice base (bytes)
        int p = pbase + l * 16;
        int row = p >> 7, slot = (p >> 4) & 7;
        int chunk = slot ^ (row & 7);      // inverse-swizzled source chunk
        size_t srcK = (size_t)(b * 2048 + kt * 64 + row) * 1024 + h * 64 + chunk * 8;
        size_t srcV = ((size_t)(h * 2 + b) * 64 + row) * 2048 + (size_t)kt * 64 + chunk * 8;
        gl_lds16(&kh[srcK], &Khb[pbase >> 1]);
        gl_lds16(&kl[srcK], &Klb[pbase >> 1]);
        gl_lds16(&vT[srcV], &Vtb[pbase >> 1]);
    }
}

// One 64-key flash step for one q-tile's state (split QK^T, exp2 softmax, PV).
__device__ __forceinline__ void attn_step(
    const unsigned short* Khb, const unsigned short* Klb, const unsigned short* Vtb,
    unsigned short* Pl, const bfrag* qfh, const bfrag* qfl,
    facc* O, float* mrow, float* lrow, int w, int l, bool diag)
{
    facc S[4];
    #pragma unroll
    for (int f = 0; f < 4; ++f) S[f] = (facc)(0.0f);
    #pragma unroll
    for (int s = 0; s < 2; ++s) {
        #pragma unroll
        for (int f = 0; f < 4; ++f) {
            int key = f * 16 + (l & 15);
            int ch = (s * 4 + (l >> 4)) ^ (key & 7);
            bfrag kbh = *(const bfrag*)&Khb[key * 64 + ch * 8];
            bfrag kbl = *(const bfrag*)&Klb[key * 64 + ch * 8];
            S[f] = MFMA(qfh[s], kbh, S[f]);
            S[f] = MFMA(qfh[s], kbl, S[f]);
            S[f] = MFMA(qfl[s], kbh, S[f]);
        }
    }
    if (diag) {
        #pragma unroll
        for (int f = 0; f < 4; ++f) {
            int keyl = f * 16 + (l & 15);
            #pragma unroll
            for (int r = 0; r < 4; ++r) {
                int qls = w * 16 + (l >> 4) * 4 + r;
                if (keyl > qls) S[f][r] = -1e30f;
            }
        }
    }
    #pragma unroll
    for (int r = 0; r < 4; ++r) {
        float mx = fmaxf(fmaxf(S[0][r], S[1][r]), fmaxf(S[2][r], S[3][r]));
        mx = fmaxf(mx, __shfl_xor(mx, 1));
        mx = fmaxf(mx, __shfl_xor(mx, 2));
        mx = fmaxf(mx, __shfl_xor(mx, 4));
        mx = fmaxf(mx, __shfl_xor(mx, 8));
        float mn = fmaxf(mrow[r], mx);
        float fac = EXP2(mrow[r] - mn);   // exp2 domain (q pre-scaled by log2e)
        mrow[r] = mn;
        float rs = 0.0f;
        #pragma unroll
        for (int f = 0; f < 4; ++f) { S[f][r] = EXP2(S[f][r] - mn); rs += S[f][r]; }
        rs += __shfl_xor(rs, 1); rs += __shfl_xor(rs, 2);
        rs += __shfl_xor(rs, 4); rs += __shfl_xor(rs, 8);
        lrow[r] = lrow[r] * fac + rs;
        O[0][r] *= fac; O[1][r] *= fac; O[2][r] *= fac; O[3][r] *= fac;
    }
    // P -> LDS (bf16, swizzled rows); same-wave rows only, lgkmcnt orders it.
    #pragma unroll
    for (int f = 0; f < 4; ++f) {
        int key = f * 16 + (l & 15);
        #pragma unroll
        for (int r = 0; r < 4; ++r) {
            int qr = w * 16 + (l >> 4) * 4 + r;
            Pl[qr * 64 + (((key >> 3) ^ (qr & 7)) * 8) + (key & 7)] = f2bh(S[f][r]);
        }
    }
    #pragma unroll
    for (int s = 0; s < 2; ++s) {
        int qa = w * 16 + (l & 15);
        int cha = (s * 4 + (l >> 4)) ^ (qa & 7);
        bfrag pa = *(const bfrag*)&Pl[qa * 64 + cha * 8];
        #pragma unroll
        for (int f = 0; f < 4; ++f) {
            int d = f * 16 + (l & 15);
            int chv = (s * 4 + (l >> 4)) ^ (d & 7);
            bfrag vb = *(const bfrag*)&Vtb[d * 64 + chv * 8];
            O[f] = MFMA(pa, vb, O[f]);
        }
    }
}

// ---------------------------------------------------------------------------
// attn_mfma: paired-q-tile flash attention.  grid (16, 32), block 256 (4 waves).
// ---------------------------------------------------------------------------
__global__ __launch_bounds__(256, 2) void attn_mfma(
    const unsigned short* __restrict__ qh, const unsigned char* __restrict__ ql8,
    const unsigned short* __restrict__ kh, const unsigned short* __restrict__ kl,
    const unsigned short* __restrict__ vT, unsigned short* __restrict__ att)
{
    __shared__ unsigned short Kh[2][64 * 64], Kl[2][64 * 64], Vt[2][64 * 64], Pl[64 * 64];
    const int tid = threadIdx.x, w = tid >> 6, l = tid & 63;
    const int dd = blockIdx.y * 16 + blockIdx.x;
    const int xcd = dd & 7, sl = dd >> 3;
    const int hb = xcd * 4 + (sl >> 4);
    const int bx = sl & 15;
    const int qtA = 31 - bx, qtB = bx;
    const int h = hb >> 1, b = hb & 1;

    bfrag qfhA[2], qflA[2], qfhB[2], qflB[2];
    {
        const int qrowA = qtA * 64 + w * 16 + (l & 15);
        const size_t qoffA = (size_t)(b * 2048 + qrowA) * 1024 + h * 64 + (l >> 4) * 8;
        qfhA[0] = *(const bfrag*)&qh[qoffA];
        qfhA[1] = *(const bfrag*)&qh[qoffA + 32];
        qflA[0] = f8frag(*(const uint2*)&ql8[qoffA]);
        qflA[1] = f8frag(*(const uint2*)&ql8[qoffA + 32]);
        const int qrowB = qtB * 64 + w * 16 + (l & 15);
        const size_t qoffB = (size_t)(b * 2048 + qrowB) * 1024 + h * 64 + (l >> 4) * 8;
        qfhB[0] = *(const bfrag*)&qh[qoffB];
        qfhB[1] = *(const bfrag*)&qh[qoffB + 32];
        qflB[0] = f8frag(*(const uint2*)&ql8[qoffB]);
        qflB[1] = f8frag(*(const uint2*)&ql8[qoffB + 32]);
    }

    facc OA[4], OB[4];
    float mA[4], lA[4], mB[4], lB[4];
    #pragma unroll
    for (int f = 0; f < 4; ++f) { OA[f] = (facc)(0.0f); OB[f] = (facc)(0.0f); }
    #pragma unroll
    for (int r = 0; r < 4; ++r) { mA[r] = -1e30f; lA[r] = 0.0f; mB[r] = -1e30f; lB[r] = 0.0f; }

    stage_kv(kh, kl, vT, Kh[0], Kl[0], Vt[0], w, l, b, h, 0);
    int cur = 0;
    for (int kt = 0; kt <= qtA; ++kt) {
        __syncthreads();
        if (kt < qtA)
            stage_kv(kh, kl, vT, Kh[cur ^ 1], Kl[cur ^ 1], Vt[cur ^ 1], w, l, b, h, kt + 1);
        __builtin_amdgcn_sched_barrier(0);
        __builtin_amdgcn_s_barrier();
        __builtin_amdgcn_sched_barrier(0);
        attn_step(Kh[cur], Kl[cur], Vt[cur], Pl, qfhA, qflA, OA, mA, lA, w, l, kt == qtA);
        if (kt <= qtB)
            attn_step(Kh[cur], Kl[cur], Vt[cur], Pl, qfhB, qflB, OB, mB, lB, w, l, kt == qtB);
        cur ^= 1;
    }

    #pragma unroll
    for (int f = 0; f < 4; ++f) {
        int d = h * 64 + f * 16 + (l & 15);
        #pragma unroll
        for (int r = 0; r < 4; ++r) {
            int tA = qtA * 64 + w * 16 + (l >> 4) * 4 + r;
            att[(size_t)(b * 2048 + tA) * 1024 + d] = f2bh(OA[f][r] / lA[r]);
            int tB = qtB * 64 + w * 16 + (l >> 4) * 4 + r;
            att[(size_t)(b * 2048 + tB) * 1024 + d] = f2bh(OB[f][r] / lB[r]);
        }
    }
}

// ---------------------------------------------------------------------------
// outproj: out[4096,1024] = att @ Wo^T.  BK=64 swizzled, double-buffered with
// the prefetch-across-raw-barrier loop.  grid (32, 8), 64KB LDS.
// ---------------------------------------------------------------------------
__global__ __launch_bounds__(256, 2) void outproj(
    const unsigned short* __restrict__ att, const unsigned short* __restrict__ WoB,
    float* __restrict__ out)
{
    __shared__ unsigned short Ab[2][128 * 64], Bb[2][128 * 64];
    const int tid = threadIdx.x, w = tid >> 6, l = tid & 63;
    const int wm = w >> 1, wn = w & 1;
    const int rt = blockIdx.x, ct = blockIdx.y;

    const int lc = (l & 7) ^ (l >> 3);         // logical chunk (0..7) -> k-offset lc*8
    facc acc[4][4];
    #pragma unroll
    for (int i = 0; i < 4; ++i)
        #pragma unroll
        for (int j = 0; j < 4; ++j) acc[i][j] = (facc)(0.0f);

    auto stage = [&](int buf, int e0) {
        #pragma unroll
        for (int i = 0; i < 4; ++i) {
            int slice = w * 4 + i;
            int row = slice * 8 + (l >> 3);
            gl_lds16(&att[(size_t)(rt * 128 + row) * 1024 + e0 + lc * 8], &Ab[buf][slice * 512]);
            gl_lds16(&WoB[(size_t)(ct * 128 + row) * 1024 + e0 + lc * 8], &Bb[buf][slice * 512]);
        }
    };

    stage(0, 0);
    int cur = 0;
    for (int t = 0; t < 16; ++t) {
        __syncthreads();
        if (t < 15) stage(cur ^ 1, (t + 1) * 64);
        __builtin_amdgcn_sched_barrier(0);
        __builtin_amdgcn_s_barrier();
        __builtin_amdgcn_sched_barrier(0);
        #pragma unroll
        for (int s = 0; s < 2; ++s) {
            const int slot = (s * 4 + (l >> 4)) ^ (l & 7);
            bfrag af[4], bf_[4];
            #pragma unroll
            for (int m = 0; m < 4; ++m)
                af[m] = *(const bfrag*)&Ab[cur][(wm * 64 + m * 16 + (l & 15)) * 64 + slot * 8];
            #pragma unroll
            for (int n = 0; n < 4; ++n)
                bf_[n] = *(const bfrag*)&Bb[cur][(wn * 64 + n * 16 + (l & 15)) * 64 + slot * 8];
            #pragma unroll
            for (int m = 0; m < 4; ++m)
                #pragma unroll
                for (int n = 0; n < 4; ++n)
                    acc[m][n] = MFMA(af[m], bf_[n], acc[m][n]);
        }
        cur ^= 1;
    }
    #pragma unroll
    for (int m = 0; m < 4; ++m)
        #pragma unroll
        for (int r = 0; r < 4; ++r) {
            int row = rt * 128 + wm * 64 + m * 16 + (l >> 4) * 4 + r;
            #pragma unroll
            for (int n = 0; n < 4; ++n) {
                int col = ct * 128 + wn * 64 + n * 16 + (l & 15);
                out[(size_t)row * 1024 + col] = acc[m][n][r];
            }
        }
}

// ---------------------------------------------------------------------------
extern "C" void kernel_launch(void* const* d_in, const int* in_sizes, int n_in,
                              void* d_out, int out_size, void* d_ws, size_t ws_size,
                              hipStream_t stream) {
    const float* x  = (const float*)d_in[0];
    // d_in[1]: causal mask (applied analytically)
    const float* Wq = (const float*)d_in[2];
    const float* Wk = (const float*)d_in[3];
    const float* Wv = (const float*)d_in[4];
    const float* Wo = (const float*)d_in[5];

    uint8_t* wsb = (uint8_t*)d_ws;
    const size_t MB = 1024 * 1024;
    // 64MB layout.  xh overlays att (xh dead before attn writes att).
    unsigned short* WqTh = (unsigned short*)(wsb + 0 * MB);
    unsigned short* WqTl = (unsigned short*)(wsb + 2 * MB);
    unsigned short* WkTh = (unsigned short*)(wsb + 4 * MB);
    unsigned short* WkTl = (unsigned short*)(wsb + 6 * MB);
    unsigned short* WvT  = (unsigned short*)(wsb + 8 * MB);
    unsigned short* qh   = (unsigned short*)(wsb + 10 * MB);  // 8MB
    unsigned char*  ql8  = (unsigned char*)(wsb + 18 * MB);   // 4MB fp8
    unsigned short* kh   = (unsigned short*)(wsb + 22 * MB);  // 8MB
    unsigned short* kl   = (unsigned short*)(wsb + 30 * MB);  // 8MB
    unsigned short* vT   = (unsigned short*)(wsb + 38 * MB);  // 8MB
    unsigned short* att  = (unsigned short*)(wsb + 46 * MB);  // 8MB
    unsigned short* xh   = (unsigned short*)(wsb + 46 * MB);  // 8MB (alias att)
    unsigned short* WoB  = (unsigned short*)(wsb + 54 * MB);  // 2MB
    unsigned short* xl   = (unsigned short*)(wsb + 56 * MB);  // 8MB

    hipFuncSetAttribute((const void*)qkv_fused,
                        hipFuncAttributeMaxDynamicSharedMemorySize, 131072);

    x_split<<<dim3(4096), 256, 0, stream>>>(x, xh, xl);
    prep_w<<<dim3(16, 16, 3), 256, 0, stream>>>(Wq, Wk, Wv, WqTh, WqTl, WkTh, WkTl, WvT);
    wo_conv<<<dim3(1024), 256, 0, stream>>>(Wo, WoB);
    qkv_fused<<<dim3(8, 32), 512, 131072, stream>>>(xh, xl, WqTh, WqTl, WkTh, WkTl, WvT,
                                                    qh, ql8, kh, kl, vT);
    attn_mfma<<<dim3(16, 32), 256, 0, stream>>>(qh, ql8, kh, kl, vT, att);
    outproj<<<dim3(32, 8), 256, 0, stream>>>(att, WoB, (float*)d_out);
}